// Round 8
// baseline (309.019 us; speedup 1.0000x reference)
//
#include <hip/hip_runtime.h>
#include <hip/hip_fp16.h>
#include <cstdint>
#include <cstddef>

#define H    50
#define TT   256      // timesteps
#define BATCH 512
#define KDIM 144      // layer-0 input dim
#define ODIM 144      // FC output dim
#define NW   32       // windows
#define WS   8        // steps per window

typedef _Float16 half8  __attribute__((ext_vector_type(8)));
typedef _Float16 half4v __attribute__((ext_vector_type(4)));
typedef float    floatx4 __attribute__((ext_vector_type(4)));
typedef int      int4v  __attribute__((ext_vector_type(4)));

__device__ __forceinline__ float rcpf(float x) { return __builtin_amdgcn_rcpf(x); }
__device__ __forceinline__ float sigm(float x) { return rcpf(1.0f + __expf(-x)); }
__device__ __forceinline__ float tanhx(float x) {
    return 1.0f - 2.0f * rcpf(__expf(2.0f * x) + 1.0f);
}

// Raw barrier: orders LDS (lgkmcnt) but leaves global loads (vmcnt) in flight.
__device__ __forceinline__ void sync_lds() {
    asm volatile("s_waitcnt lgkmcnt(0)\n\ts_barrier" ::: "memory");
}
// Wave-local LDS write->read ordering (used once per window after gp scatter).
__device__ __forceinline__ void wave_lds_fence() {
    asm volatile("s_waitcnt lgkmcnt(0)" ::: "memory");
}

// ---------- A-fragment builders (A layout: row m = lane&15, k = q*8 + j) ----------
// K=64 hidden-matmul rows (Whh0 / Whh1): k<50 = W[p][k], else 0.
__device__ __forceinline__ half8 make_hh(const float* __restrict__ Wt,
                                         int kkA, int gate, int q, int s) {
    const float* r0 = Wt + (size_t)(gate * H + (kkA < H ? kkA : 0)) * H;
    half8 r;
    #pragma unroll
    for (int j = 0; j < 8; ++j) {
        const int k = s * 32 + q * 8 + j;
        r[j] = (_Float16)((kkA < H && k < H) ? r0[k] : 0.0f);
    }
    return r;
}
// x-projection rows: K=160 pad; k<144 = W_ih0, k==144 = bias0 (rides 1.0 B-channel)
__device__ __forceinline__ half8 make_ax(const float* __restrict__ Wih0,
                                         const float* __restrict__ bih0,
                                         const float* __restrict__ bhh0,
                                         int kkA, int gate, int q, int s) {
    const int p = gate * H + (kkA < H ? kkA : 0);
    half8 r;
    #pragma unroll
    for (int j = 0; j < 8; ++j) {
        const int k = s * 32 + q * 8 + j;
        float v = 0.0f;
        if (kkA < H) {
            if (k < KDIM)        v = Wih0[(size_t)p * KDIM + k];
            else if (k == KDIM)  v = bih0[p] + bhh0[p];
        }
        r[j] = (_Float16)v;
    }
    return r;
}
// L1 input-projection rows (over h0 window): K=64; k<50 = W_ih1, k==50 = bias1.
__device__ __forceinline__ half8 make_p1(const float* __restrict__ Wih1,
                                         const float* __restrict__ bih1,
                                         const float* __restrict__ bhh1,
                                         int kkA, int gate, int q, int s) {
    const int p = gate * H + (kkA < H ? kkA : 0);
    half8 r;
    #pragma unroll
    for (int j = 0; j < 8; ++j) {
        const int k = s * 32 + q * 8 + j;
        float v = 0.0f;
        if (kkA < H) {
            if (k < H)           v = Wih1[(size_t)p * H + k];
            else if (k == H)     v = bih1[p] + bhh1[p];
        }
        r[j] = (_Float16)v;
    }
    return r;
}

// ---------- Single fused kernel: 4 waves (1/SIMD), broadcast-B, in-reg select ----------
// Each wave owns 4 A-tiles per layer (units 16w+4tl+q). The h B-fragment is read
// with col&1 (LDS broadcast) so EVERY C column holds a valid gate quad: col c =
// gates for batch row c&1. Lane (col,q) acts on quad col>>1 = (tl=c2&3, L=c2>>2),
// selected from its own MFMA result registers by a cndmask tree — no LDS bounce,
// no fence in the step. One raw s_barrier per step. L1 input-proj batched per
// 8-step window (gp1), L0 x-proj batched per window (gp0).
__global__ __launch_bounds__(256, 1) void lstm_fused(
    const float* __restrict__ X,
    const float* __restrict__ Whh0, const float* __restrict__ Wih0,
    const float* __restrict__ bih0, const float* __restrict__ bhh0,
    const float* __restrict__ Wih1, const float* __restrict__ Whh1,
    const float* __restrict__ bih1, const float* __restrict__ bhh1,
    const float* __restrict__ Wfc, const float* __restrict__ bfc,
    float* __restrict__ out)
{
    const int b0   = blockIdx.x * 2;
    const int tid  = threadIdx.x;    // 0..255
    const int lane = tid & 63;
    const int w    = tid >> 6;       // wave 0..3
    const int col  = lane & 15;      // C col
    const int q    = lane >> 4;      // 0..3

    __shared__ __align__(16) _Float16 B0[2][2][4][2][8];    // h0 [buf][s][q][r][j] (2 rows only)
    __shared__ __align__(16) _Float16 B1[2][2][4][2][8];    // h1
    __shared__ __align__(16) _Float16 HW[2][2][4][16][8];   // h0 window [wbuf][s][q][2t+r][j], 1.0@k=50
    __shared__ __align__(16) float    gp0[64 * 72];         // L0 xproj quads [u][t*8+r*4+g]
    __shared__ __align__(16) float    gp1[64 * 72];         // L1 h0proj quads
    __shared__ __align__(16) _Float16 XB[2][5][4][16][8];   // x B-frags [buf][s][q][2t+r][j], 1.0@k=144
    __shared__ float h1f[2][52];

    // ---- inline A-prep: 44 frags/thread (4 tiles x {hh0:2, x:5, hh1:2, p1:2}) ----
    int4v Ap[44];
    {
        const int prow = lane & 15;
        const int gate = prow & 3;
        #pragma unroll
        for (int tl = 0; tl < 4; ++tl) {
            const int kkA = 16 * w + 4 * tl + (prow >> 2);
            #pragma unroll
            for (int s = 0; s < 2; ++s) Ap[tl * 2 + s]      = __builtin_bit_cast(int4v, make_hh(Whh0, kkA, gate, q, s));
            #pragma unroll
            for (int s = 0; s < 5; ++s) Ap[8 + tl * 5 + s]  = __builtin_bit_cast(int4v, make_ax(Wih0, bih0, bhh0, kkA, gate, q, s));
            #pragma unroll
            for (int s = 0; s < 2; ++s) Ap[28 + tl * 2 + s] = __builtin_bit_cast(int4v, make_hh(Whh1, kkA, gate, q, s));
            #pragma unroll
            for (int s = 0; s < 2; ++s) Ap[36 + tl * 2 + s] = __builtin_bit_cast(int4v, make_p1(Wih1, bih1, bhh1, kkA, gate, q, s));
        }
    }
    #pragma unroll
    for (int i = 0; i < 44; ++i) asm volatile("" : "+a"(Ap[i]));

    // ---- act decode: every lane owns ONE cell ----
    const int  c2  = col >> 1;           // quad index 0..7
    const int  r   = col & 1;            // batch row
    const int  atl = c2 & 3;             // tile
    const int  aL  = c2 >> 2;            // layer
    const int  au  = 16 * w + 4 * atl + q;
    const bool areal = (au < H);
    float c = 0.0f;
    const float* gpb = (aL ? gp1 : gp0) + au * 72;

    // ---- x-stage decode: 576 float4/window over 256 threads (2-3 each) ----
    const int cs1 = tid / 36,          kk1 = tid % 36;
    const int cs2 = (tid + 256) / 36,  kk2 = (tid + 256) % 36;
    const int cs3 = (tid + 512) / 36,  kk3 = (tid + 512) % 36;   // only tid<64
    const float* xq1 = X + ((size_t)(b0 + (cs1 & 1)) * TT + (cs1 >> 1)) * KDIM + kk1 * 4;
    const float* xq2 = X + ((size_t)(b0 + (cs2 & 1)) * TT + (cs2 >> 1)) * KDIM + kk2 * 4;
    const float* xq3 = X + ((size_t)(b0 + (cs3 & 1)) * TT + (cs3 >> 1)) * KDIM + kk3 * 4;

    // ---- init: zero B0/B1/HW/XB, set 1.0 channels, stage XB[0] ----
    if (tid < 128) { ((int*)B0)[tid] = 0; ((int*)B1)[tid] = 0; }
    for (int i = tid; i < 1024; i += 256) ((int*)HW)[i] = 0;
    for (int i = tid; i < 2560; i += 256) ((int*)XB)[i] = 0;
    __syncthreads();
    if (tid < 32) {
        HW[tid >> 4][1][2][tid & 15][2] = (_Float16)1.0f;  // k=50 bias1 channel
        XB[tid >> 4][4][2][tid & 15][0] = (_Float16)1.0f;  // k=144 bias0 channel
    }
    {
        const float4 v1 = *(const float4*)xq1;
        half4v h; h[0]=(_Float16)v1.x; h[1]=(_Float16)v1.y; h[2]=(_Float16)v1.z; h[3]=(_Float16)v1.w;
        *(half4v*)&XB[0][kk1 >> 3][(kk1 >> 1) & 3][cs1][(kk1 & 1) * 4] = h;
        const float4 v2 = *(const float4*)xq2;
        half4v h2; h2[0]=(_Float16)v2.x; h2[1]=(_Float16)v2.y; h2[2]=(_Float16)v2.z; h2[3]=(_Float16)v2.w;
        *(half4v*)&XB[0][kk2 >> 3][(kk2 >> 1) & 3][cs2][(kk2 & 1) * 4] = h2;
        if (tid < 64) {
            const float4 v3 = *(const float4*)xq3;
            half4v h3; h3[0]=(_Float16)v3.x; h3[1]=(_Float16)v3.y; h3[2]=(_Float16)v3.z; h3[3]=(_Float16)v3.w;
            *(half4v*)&XB[0][kk3 >> 3][(kk3 >> 1) & 3][cs3][(kk3 & 1) * 4] = h3;
        }
    }
    __syncthreads();

    const int gb = (col >> 1) * 8 + (col & 1) * 4;   // window-top scatter offset

    for (int W = 0; W < NW; ++W) {
        #pragma unroll
        for (int i = 0; i < 44; ++i) asm volatile("" : "+a"(Ap[i]));
        const int cb = W & 1, nb = cb ^ 1, pb = cb ^ 1;
        const bool more = (W + 1) < NW;
        float4 xv1, xv2, xv3;
        if (more) {
            xv1 = *(const float4*)(xq1 + (size_t)(W + 1) * WS * KDIM);
            xv2 = *(const float4*)(xq2 + (size_t)(W + 1) * WS * KDIM);
            if (tid < 64) xv3 = *(const float4*)(xq3 + (size_t)(W + 1) * WS * KDIM);
        }
        // ---- window top: L0 x-proj (16 cols = 8t x 2r) ----
        {
            half8 xbf[5];
            #pragma unroll
            for (int s = 0; s < 5; ++s) xbf[s] = *(const half8*)&XB[cb][s][q][col][0];
            #pragma unroll
            for (int tl = 0; tl < 4; ++tl) {
                floatx4 px = (floatx4)(0.0f);
                #pragma unroll
                for (int s = 0; s < 5; ++s)
                    px = __builtin_amdgcn_mfma_f32_16x16x32_f16(__builtin_bit_cast(half8, Ap[8 + tl * 5 + s]), xbf[s], px, 0, 0, 0);
                *(floatx4*)&gp0[(16 * w + 4 * tl + q) * 72 + gb] = px;
            }
        }
        // ---- window top: L1 h0-proj+bias1 over previous window's h0 ----
        if (W > 0) {
            half8 hbf[2];
            #pragma unroll
            for (int s = 0; s < 2; ++s) hbf[s] = *(const half8*)&HW[pb][s][q][col][0];
            #pragma unroll
            for (int tl = 0; tl < 4; ++tl) {
                floatx4 pw = (floatx4)(0.0f);
                #pragma unroll
                for (int s = 0; s < 2; ++s)
                    pw = __builtin_amdgcn_mfma_f32_16x16x32_f16(__builtin_bit_cast(half8, Ap[36 + tl * 2 + s]), hbf[s], pw, 0, 0, 0);
                *(floatx4*)&gp1[(16 * w + 4 * tl + q) * 72 + gb] = pw;
            }
        }
        wave_lds_fence();   // gp scatter -> same-wave act reads
        // ---- 8 serial steps ----
        #pragma unroll
        for (int i = 0; i < WS; ++i) {
            const int rb = i & 1, wb = rb ^ 1;
            half8 bf0[2], bf1[2];
            #pragma unroll
            for (int s = 0; s < 2; ++s) {
                bf0[s] = *(const half8*)&B0[rb][s][q][r][0];   // broadcast read
                bf1[s] = *(const half8*)&B1[rb][s][q][r][0];
            }
            const floatx4 gx = *(const floatx4*)&gpb[i * 8 + r * 4];
            floatx4 a0[4], a1[4];
            #pragma unroll
            for (int tl = 0; tl < 4; ++tl) { a0[tl] = (floatx4)(0.0f); a1[tl] = (floatx4)(0.0f); }
            #pragma unroll
            for (int tl = 0; tl < 4; ++tl) {
                #pragma unroll
                for (int s = 0; s < 2; ++s) {
                    a0[tl] = __builtin_amdgcn_mfma_f32_16x16x32_f16(__builtin_bit_cast(half8, Ap[tl*2+s]),    bf0[s], a0[tl], 0, 0, 0);
                    a1[tl] = __builtin_amdgcn_mfma_f32_16x16x32_f16(__builtin_bit_cast(half8, Ap[28+tl*2+s]), bf1[s], a1[tl], 0, 0, 0);
                }
            }
            // ---- in-register quad select (7 cndmask per gate) ----
            floatx4 g;
            #pragma unroll
            for (int gi_ = 0; gi_ < 4; ++gi_) {
                const float s01 = (c2 & 1) ? a0[1][gi_] : a0[0][gi_];
                const float s23 = (c2 & 1) ? a0[3][gi_] : a0[2][gi_];
                const float s45 = (c2 & 1) ? a1[1][gi_] : a1[0][gi_];
                const float s67 = (c2 & 1) ? a1[3][gi_] : a1[2][gi_];
                const float e0  = (c2 & 2) ? s23 : s01;
                const float e1  = (c2 & 2) ? s67 : s45;
                g[gi_] = (c2 & 4) ? e1 : e0;
            }
            // ---- act: one cell per lane ----
            if (aL == 0 || W > 0) {
                g[0] += gx[0]; g[1] += gx[1]; g[2] += gx[2]; g[3] += gx[3];
                const float gi = sigm(g[0]), gf = sigm(g[1]);
                const float gg = tanhx(g[2]), go = sigm(g[3]);
                c = gf * c + gi * gg;
                const float hv = go * tanhx(c);
                if (areal) {
                    const _Float16 h16 = (_Float16)hv;
                    if (aL == 0) {
                        B0[wb][au >> 5][(au >> 3) & 3][r][au & 7] = h16;
                        HW[cb][au >> 5][(au >> 3) & 3][2 * i + r][au & 7] = h16;
                    } else {
                        B1[wb][au >> 5][(au >> 3) & 3][r][au & 7] = h16;
                    }
                }
            }
            // mid-window: stage next-window x into XB[nb] (loads long in flight)
            if (i == 3 && more) {
                half4v h; h[0]=(_Float16)xv1.x; h[1]=(_Float16)xv1.y; h[2]=(_Float16)xv1.z; h[3]=(_Float16)xv1.w;
                *(half4v*)&XB[nb][kk1 >> 3][(kk1 >> 1) & 3][cs1][(kk1 & 1) * 4] = h;
                half4v h2; h2[0]=(_Float16)xv2.x; h2[1]=(_Float16)xv2.y; h2[2]=(_Float16)xv2.z; h2[3]=(_Float16)xv2.w;
                *(half4v*)&XB[nb][kk2 >> 3][(kk2 >> 1) & 3][cs2][(kk2 & 1) * 4] = h2;
                if (tid < 64) {
                    half4v h3; h3[0]=(_Float16)xv3.x; h3[1]=(_Float16)xv3.y; h3[2]=(_Float16)xv3.z; h3[3]=(_Float16)xv3.w;
                    *(half4v*)&XB[nb][kk3 >> 3][(kk3 >> 1) & 3][cs3][(kk3 & 1) * 4] = h3;
                }
            }
            sync_lds();         // B0/B1[wb], HW[cb], XB[nb] -> next step
        }
    }
    // ---- tail window: L1 for t' = TT-8 .. TT-1 ----
    {
        #pragma unroll
        for (int i = 0; i < 44; ++i) asm volatile("" : "+a"(Ap[i]));
        {
            half8 hbf[2];
            #pragma unroll
            for (int s = 0; s < 2; ++s) hbf[s] = *(const half8*)&HW[(NW - 1) & 1][s][q][col][0];
            #pragma unroll
            for (int tl = 0; tl < 4; ++tl) {
                floatx4 pw = (floatx4)(0.0f);
                #pragma unroll
                for (int s = 0; s < 2; ++s)
                    pw = __builtin_amdgcn_mfma_f32_16x16x32_f16(__builtin_bit_cast(half8, Ap[36 + tl * 2 + s]), hbf[s], pw, 0, 0, 0);
                *(floatx4*)&gp1[(16 * w + 4 * tl + q) * 72 + gb] = pw;
            }
        }
        wave_lds_fence();
        #pragma unroll
        for (int i = 0; i < WS; ++i) {
            const int rb = i & 1, wb = rb ^ 1;
            half8 bf1[2];
            #pragma unroll
            for (int s = 0; s < 2; ++s) bf1[s] = *(const half8*)&B1[rb][s][q][r][0];
            const floatx4 gx = *(const floatx4*)&gpb[i * 8 + r * 4];
            floatx4 a1[4];
            #pragma unroll
            for (int tl = 0; tl < 4; ++tl) {
                a1[tl] = (floatx4)(0.0f);
                #pragma unroll
                for (int s = 0; s < 2; ++s)
                    a1[tl] = __builtin_amdgcn_mfma_f32_16x16x32_f16(__builtin_bit_cast(half8, Ap[28+tl*2+s]), bf1[s], a1[tl], 0, 0, 0);
            }
            if (aL == 1) {
                floatx4 g;
                #pragma unroll
                for (int gi_ = 0; gi_ < 4; ++gi_) {
                    const float s01 = (c2 & 1) ? a1[1][gi_] : a1[0][gi_];
                    const float s23 = (c2 & 1) ? a1[3][gi_] : a1[2][gi_];
                    g[gi_] = (c2 & 2) ? s23 : s01;
                }
                g[0] += gx[0]; g[1] += gx[1]; g[2] += gx[2]; g[3] += gx[3];
                const float gi = sigm(g[0]), gf = sigm(g[1]);
                const float gg = tanhx(g[2]), go = sigm(g[3]);
                c = gf * c + gi * gg;
                const float hv = go * tanhx(c);
                if (areal) {
                    B1[wb][au >> 5][(au >> 3) & 3][r][au & 7] = (_Float16)hv;
                    if (i == WS - 1) h1f[r][au] = hv;
                }
            }
            sync_lds();
        }
    }
    // ---- fused FC on h1(TT-1): 2 rows x 144 outs over 256 threads ----
    for (int oo = tid; oo < 2 * ODIM; oo += 256) {
        const int rr = oo / ODIM, o = oo - rr * ODIM;
        float s = bfc[o];
        const float* wr = Wfc + (size_t)o * H;
        #pragma unroll
        for (int k = 0; k < H; ++k) s += wr[k] * h1f[rr][k];
        out[(size_t)(b0 + rr) * ODIM + o] = s;
    }
}

extern "C" void kernel_launch(void* const* d_in, const int* in_sizes, int n_in,
                              void* d_out, int out_size, void* d_ws, size_t ws_size,
                              hipStream_t stream) {
    const float* x    = (const float*)d_in[0];
    const float* wih0 = (const float*)d_in[1];
    const float* whh0 = (const float*)d_in[2];
    const float* bih0 = (const float*)d_in[3];
    const float* bhh0 = (const float*)d_in[4];
    const float* wih1 = (const float*)d_in[5];
    const float* whh1 = (const float*)d_in[6];
    const float* bih1 = (const float*)d_in[7];
    const float* bhh1 = (const float*)d_in[8];
    const float* wfc  = (const float*)d_in[9];
    const float* bfc  = (const float*)d_in[10];
    float* outp = (float*)d_out;

    lstm_fused<<<BATCH / 2, 256, 0, stream>>>(x, whh0, wih0, bih0, bhh0,
                                              wih1, whh1, bih1, bhh1,
                                              wfc, bfc, outp);
}

// Round 9
// 249.271 us; speedup vs baseline: 1.2397x; 1.2397x over previous
//
#include <hip/hip_runtime.h>
#include <hip/hip_fp16.h>
#include <cstdint>
#include <cstddef>

#define H    50
#define TT   256      // timesteps
#define BATCH 512
#define KDIM 144      // layer-0 input dim
#define ODIM 144      // FC output dim
#define NW   32       // windows
#define WS   8        // steps per window

typedef _Float16 half8  __attribute__((ext_vector_type(8)));
typedef _Float16 half4v __attribute__((ext_vector_type(4)));
typedef float    floatx4 __attribute__((ext_vector_type(4)));
typedef int      int4v  __attribute__((ext_vector_type(4)));

__device__ __forceinline__ float rcpf(float x) { return __builtin_amdgcn_rcpf(x); }
__device__ __forceinline__ float sigm(float x) { return rcpf(1.0f + __expf(-x)); }
__device__ __forceinline__ float tanhx(float x) {
    return 1.0f - 2.0f * rcpf(__expf(2.0f * x) + 1.0f);
}

// Raw barrier: orders LDS (lgkmcnt) but leaves global loads (vmcnt) in flight.
__device__ __forceinline__ void sync_lds() {
    asm volatile("s_waitcnt lgkmcnt(0)\n\ts_barrier" ::: "memory");
}

// ---------- A-fragment builders (A layout: row m = lane&15, k = q*8 + j) ----------
__device__ __forceinline__ half8 make_a0(const float* __restrict__ Whh0,
                                         int kkA, int gate, int q, int s) {
    const float* r0 = Whh0 + (size_t)(gate * H + (kkA < H ? kkA : 0)) * H;
    half8 r;
    #pragma unroll
    for (int j = 0; j < 8; ++j) {
        const int k = s * 32 + q * 8 + j;
        r[j] = (_Float16)((kkA < H && k < H) ? r0[k] : 0.0f);
    }
    return r;
}
// x-projection rows: K=160 pad; k<144 = W_ih0, k==144 = bias0 (rides 1.0 B-channel)
__device__ __forceinline__ half8 make_ax(const float* __restrict__ Wih0,
                                         const float* __restrict__ bih0,
                                         const float* __restrict__ bhh0,
                                         int kkA, int gate, int q, int s) {
    const int p = gate * H + (kkA < H ? kkA : 0);
    half8 r;
    #pragma unroll
    for (int j = 0; j < 8; ++j) {
        const int k = s * 32 + q * 8 + j;
        float v = 0.0f;
        if (kkA < H) {
            if (k < KDIM)        v = Wih0[(size_t)p * KDIM + k];
            else if (k == KDIM)  v = bih0[p] + bhh0[p];
        }
        r[j] = (_Float16)v;
    }
    return r;
}
// layer-1 rows: K=128 pad; k<50 = W_ih1 (over h0), 50..99 = W_hh1 (over h1), k==100 = bias1
__device__ __forceinline__ half8 make_a1(const float* __restrict__ Wih1,
                                         const float* __restrict__ Whh1,
                                         const float* __restrict__ bih1,
                                         const float* __restrict__ bhh1,
                                         int kkA, int gate, int q, int s) {
    const int p = gate * H + (kkA < H ? kkA : 0);
    half8 r;
    #pragma unroll
    for (int j = 0; j < 8; ++j) {
        const int k = s * 32 + q * 8 + j;
        float v = 0.0f;
        if (kkA < H) {
            if (k < H)            v = Wih1[(size_t)p * H + k];
            else if (k < 2 * H)   v = Whh1[(size_t)p * H + (k - H)];
            else if (k == 100)    v = bih1[p] + bhh1[p];
        }
        r[j] = (_Float16)v;
    }
    return r;
}

// ---------- Fused kernel: R2 base (8 waves, 2/SIMD) + broadcast-B cndmask select ----------
// h B-fragment read at col&1 (LDS same-address broadcast) -> every C column holds a
// valid gate quad: col c = gates of batch row c&1. Lane (col,q) selects its quad
// (tl,L) = ((col>>1)&1, (col>>1)>>1) from its own a0/a1 regs via 12 cndmask — no scr
// LDS bounce, no fence in the step. One raw s_barrier per step. x-proj batched
// 8 steps/window into gp; L1 in-step at K=128 over [h0;h1;bias] (lags one step).
__global__ __launch_bounds__(512, 1) void lstm_fused(
    const float* __restrict__ X,
    const float* __restrict__ Whh0, const float* __restrict__ Wih0,
    const float* __restrict__ bih0, const float* __restrict__ bhh0,
    const float* __restrict__ Wih1, const float* __restrict__ Whh1,
    const float* __restrict__ bih1, const float* __restrict__ bhh1,
    const float* __restrict__ Wfc, const float* __restrict__ bfc,
    float* __restrict__ out)
{
    const int b0   = blockIdx.x * 2;
    const int tid  = threadIdx.x;
    const int lane = tid & 63;
    const int w    = tid >> 6;       // wave 0..7
    const int col  = lane & 15;      // C col
    const int q    = lane >> 4;      // 0..3

    __shared__ __align__(16) _Float16 B2[2][4][4][2][8];    // h-state [buf][s][q][r][j], 2 rows
    __shared__ __align__(16) float    gp[64 * 72];          // xproj quads [u][t*8+r*4+g]
    __shared__ __align__(16) _Float16 XB[2][5][4][16][8];   // x B-frags [buf][s][q][2t+r][j], 1.0@k=144
    __shared__ float h1f[2][52];

    // ---- inline A-prep: each block bakes its own 22 frags (L2-broadcast reads) ----
    int4v Ap[22];
    {
        const int prow = lane & 15;
        const int gate = prow & 3;
        const int kkA0 = 8 * w + 0 + (prow >> 2);
        const int kkA1 = 8 * w + 4 + (prow >> 2);
        Ap[0] = __builtin_bit_cast(int4v, make_a0(Whh0, kkA0, gate, q, 0));
        Ap[1] = __builtin_bit_cast(int4v, make_a0(Whh0, kkA0, gate, q, 1));
        Ap[2] = __builtin_bit_cast(int4v, make_a0(Whh0, kkA1, gate, q, 0));
        Ap[3] = __builtin_bit_cast(int4v, make_a0(Whh0, kkA1, gate, q, 1));
        #pragma unroll
        for (int s = 0; s < 5; ++s) Ap[4 + s] = __builtin_bit_cast(int4v, make_ax(Wih0, bih0, bhh0, kkA0, gate, q, s));
        #pragma unroll
        for (int s = 0; s < 5; ++s) Ap[9 + s] = __builtin_bit_cast(int4v, make_ax(Wih0, bih0, bhh0, kkA1, gate, q, s));
        #pragma unroll
        for (int s = 0; s < 4; ++s) Ap[14 + s] = __builtin_bit_cast(int4v, make_a1(Wih1, Whh1, bih1, bhh1, kkA0, gate, q, s));
        #pragma unroll
        for (int s = 0; s < 4; ++s) Ap[18 + s] = __builtin_bit_cast(int4v, make_a1(Wih1, Whh1, bih1, bhh1, kkA1, gate, q, s));
    }
    #pragma unroll
    for (int i = 0; i < 22; ++i) asm volatile("" : "+a"(Ap[i]));

    // ---- act decode: lane (col,q) owns cell (unit au, layer aL, row r) ----
    const int  c2m  = (col >> 1) & 3;    // quad select (cols 8..15 duplicate, masked)
    const int  r    = col & 1;           // batch row
    const int  atl  = c2m & 1;           // tile
    const int  aL   = c2m >> 1;          // layer
    const int  au   = 8 * w + 4 * atl + q;
    const int  ak   = aL * H + au;
    const bool valid = (col < 8);
    const bool areal = (au < H);
    float c = 0.0f;

    // ---- x-stage decode: 576 float4/window over 512(+64) threads ----
    const int cs1 = tid / 36,         kk1 = tid % 36;
    const int cs2 = (tid + 512) / 36, kk2 = (tid + 512) % 36;
    const float* xp1 = X + ((size_t)(b0 + (cs1 & 1)) * TT + (cs1 >> 1)) * KDIM + kk1 * 4;
    const float* xp2 = X + ((size_t)(b0 + (cs2 & 1)) * TT + (cs2 >> 1)) * KDIM + kk2 * 4;

    // ---- init: zero B2 + XB, set 1.0 channels, stage XB[0] (tokens 0..7) ----
    if (tid < 256) ((int*)B2)[tid] = 0;
    for (int i = tid; i < 2560; i += 512) ((int*)XB)[i] = 0;
    __syncthreads();
    if (tid < 4)  B2[tid >> 1][3][0][tid & 1][4]  = (_Float16)1.0f;  // k=100 bias1
    if (tid < 32) XB[tid >> 4][4][2][tid & 15][0] = (_Float16)1.0f;  // k=144 bias0
    {
        const float4 v1 = *(const float4*)xp1;
        const int s = kk1 >> 3, qq = (kk1 >> 1) & 3, j0 = (kk1 & 1) * 4;
        half4v h; h[0]=(_Float16)v1.x; h[1]=(_Float16)v1.y; h[2]=(_Float16)v1.z; h[3]=(_Float16)v1.w;
        *(half4v*)&XB[0][s][qq][cs1][j0] = h;
        if (tid < 64) {
            const float4 v2 = *(const float4*)xp2;
            const int s2 = kk2 >> 3, q2 = (kk2 >> 1) & 3, j2 = (kk2 & 1) * 4;
            half4v h2; h2[0]=(_Float16)v2.x; h2[1]=(_Float16)v2.y; h2[2]=(_Float16)v2.z; h2[3]=(_Float16)v2.w;
            *(half4v*)&XB[0][s2][q2][cs2][j2] = h2;
        }
    }
    __syncthreads();

    const int gb = (col >> 1) * 8 + (col & 1) * 4;   // proj scatter offset (t*8 + r*4)

    for (int W = 0; W < NW; ++W) {
        #pragma unroll
        for (int i = 0; i < 22; ++i) asm volatile("" : "+a"(Ap[i]));
        const int cb = W & 1, nb = cb ^ 1;
        const bool more = (W + 1) < NW;
        // issue next-window x loads (consumed at step 3 -> latency hidden)
        float4 xv1, xv2;
        if (more) {
            xv1 = *(const float4*)(xp1 + (size_t)(W + 1) * WS * KDIM);
            if (tid < 64) xv2 = *(const float4*)(xp2 + (size_t)(W + 1) * WS * KDIM);
        }
        // ---- window-top proj: xproj+bias0 for 16 tokens (8t x 2r) ----
        {
            half8 xbf[5];
            #pragma unroll
            for (int s = 0; s < 5; ++s) xbf[s] = *(const half8*)&XB[cb][s][q][col][0];
            floatx4 px0 = (floatx4)(0.0f), px1 = (floatx4)(0.0f);
            #pragma unroll
            for (int s = 0; s < 5; ++s) {
                px0 = __builtin_amdgcn_mfma_f32_16x16x32_f16(__builtin_bit_cast(half8, Ap[4 + s]), xbf[s], px0, 0, 0, 0);
                px1 = __builtin_amdgcn_mfma_f32_16x16x32_f16(__builtin_bit_cast(half8, Ap[9 + s]), xbf[s], px1, 0, 0, 0);
            }
            // wave-private scatter: lane(c,q) reg g -> token c, unit 8w+4tl+q, gate g
            *(floatx4*)&gp[(8 * w + q) * 72 + gb]     = px0;
            *(floatx4*)&gp[(8 * w + 4 + q) * 72 + gb] = px1;
        }
        // ---- 8 recurrent steps ----
        #pragma unroll
        for (int i = 0; i < WS; ++i) {
            const int rb = i & 1, wb = rb ^ 1;
            half8 bf[4];
            #pragma unroll
            for (int s = 0; s < 4; ++s) bf[s] = *(const half8*)&B2[rb][s][q][r][0];   // broadcast
            // pre-issue gp read (consumed after MFMA -> latency hidden); 2-way banks = free
            const floatx4 gx = *(const floatx4*)&gp[au * 72 + i * 8 + r * 4];
            floatx4 a0[2], a1[2];
            #pragma unroll
            for (int tl = 0; tl < 2; ++tl) { a0[tl] = (floatx4)(0.0f); a1[tl] = (floatx4)(0.0f); }
            #pragma unroll
            for (int tl = 0; tl < 2; ++tl) {
                a0[tl] = __builtin_amdgcn_mfma_f32_16x16x32_f16(__builtin_bit_cast(half8, Ap[tl*2+0]), bf[0], a0[tl], 0, 0, 0);
                a0[tl] = __builtin_amdgcn_mfma_f32_16x16x32_f16(__builtin_bit_cast(half8, Ap[tl*2+1]), bf[1], a0[tl], 0, 0, 0);
                #pragma unroll
                for (int s = 0; s < 4; ++s)
                    a1[tl] = __builtin_amdgcn_mfma_f32_16x16x32_f16(__builtin_bit_cast(half8, Ap[14+tl*4+s]), bf[s], a1[tl], 0, 0, 0);
            }
            // ---- in-register quad select (12 cndmask) ----
            floatx4 g;
            #pragma unroll
            for (int gi_ = 0; gi_ < 4; ++gi_) {
                const float s01 = (c2m & 1) ? a0[1][gi_] : a0[0][gi_];
                const float s23 = (c2m & 1) ? a1[1][gi_] : a1[0][gi_];
                g[gi_] = (c2m & 2) ? s23 : s01;
            }
            if (aL == 0) { g[0] += gx[0]; g[1] += gx[1]; g[2] += gx[2]; g[3] += gx[3]; }
            // ---- act: one cell per lane (branchless c update; L1 lags: dead at t==0) ----
            const float gi = sigm(g[0]), gf = sigm(g[1]);
            const float gg = tanhx(g[2]), go = sigm(g[3]);
            const bool en = (aL == 0) || (W > 0) || (i > 0);
            const float cn = gf * c + gi * gg;
            c = en ? cn : c;
            const float hv = go * tanhx(c);
            if (valid && areal && en)
                B2[wb][ak >> 5][(ak >> 3) & 3][r][ak & 7] = (_Float16)hv;
            // mid-window: write next-window x into XB[nb] (loads long in flight)
            if (i == 3 && more) {
                {
                    const int s = kk1 >> 3, qq = (kk1 >> 1) & 3, j0 = (kk1 & 1) * 4;
                    half4v h; h[0]=(_Float16)xv1.x; h[1]=(_Float16)xv1.y; h[2]=(_Float16)xv1.z; h[3]=(_Float16)xv1.w;
                    *(half4v*)&XB[nb][s][qq][cs1][j0] = h;
                }
                if (tid < 64) {
                    const int s2 = kk2 >> 3, q2 = (kk2 >> 1) & 3, j2 = (kk2 & 1) * 4;
                    half4v h2; h2[0]=(_Float16)xv2.x; h2[1]=(_Float16)xv2.y; h2[2]=(_Float16)xv2.z; h2[3]=(_Float16)xv2.w;
                    *(half4v*)&XB[nb][s2][q2][cs2][j2] = h2;
                }
            }
            sync_lds();         // B2[wb]/XB[nb] -> next step
        }
    }
    // ---- tail: gates1(TT-1) from B2[0] = [h0(TT-1); h1(TT-2); 1.0] ----
    {
        half8 bf[4];
        #pragma unroll
        for (int s = 0; s < 4; ++s) bf[s] = *(const half8*)&B2[0][s][q][r][0];
        floatx4 a1[2];
        #pragma unroll
        for (int tl = 0; tl < 2; ++tl) {
            a1[tl] = (floatx4)(0.0f);
            #pragma unroll
            for (int s = 0; s < 4; ++s)
                a1[tl] = __builtin_amdgcn_mfma_f32_16x16x32_f16(__builtin_bit_cast(half8, Ap[14+tl*4+s]), bf[s], a1[tl], 0, 0, 0);
        }
        floatx4 g;
        #pragma unroll
        for (int gi_ = 0; gi_ < 4; ++gi_)
            g[gi_] = (c2m & 1) ? a1[1][gi_] : a1[0][gi_];
        const float gi = sigm(g[0]), gf = sigm(g[1]);
        const float gg = tanhx(g[2]), go = sigm(g[3]);
        const float cn = gf * c + gi * gg;
        const float hv = go * tanhx(cn);
        if (valid && aL == 1 && areal) h1f[r][au] = hv;
        sync_lds();
    }
    // ---- fused FC on h1(TT-1): 2 rows x 144 outs ----
    if (tid < 2 * ODIM) {
        const int rr = tid / ODIM, o = tid - rr * ODIM;
        float s = bfc[o];
        const float* wr = Wfc + (size_t)o * H;
        #pragma unroll
        for (int k = 0; k < H; ++k) s += wr[k] * h1f[rr][k];
        out[(size_t)(b0 + rr) * ODIM + o] = s;
    }
}

extern "C" void kernel_launch(void* const* d_in, const int* in_sizes, int n_in,
                              void* d_out, int out_size, void* d_ws, size_t ws_size,
                              hipStream_t stream) {
    const float* x    = (const float*)d_in[0];
    const float* wih0 = (const float*)d_in[1];
    const float* whh0 = (const float*)d_in[2];
    const float* bih0 = (const float*)d_in[3];
    const float* bhh0 = (const float*)d_in[4];
    const float* wih1 = (const float*)d_in[5];
    const float* whh1 = (const float*)d_in[6];
    const float* bih1 = (const float*)d_in[7];
    const float* bhh1 = (const float*)d_in[8];
    const float* wfc  = (const float*)d_in[9];
    const float* bfc  = (const float*)d_in[10];
    float* outp = (float*)d_out;

    lstm_fused<<<BATCH / 2, 512, 0, stream>>>(x, whh0, wih0, bih0, bhh0,
                                              wih1, whh1, bih1, bhh1,
                                              wfc, bfc, outp);
}